// Round 5
// baseline (575.795 us; speedup 1.0000x reference)
//
#include <hip/hip_runtime.h>
#include <stdint.h>

#define Bn   2048
#define Nn   20
#define Dn   512
#define Hn   8
#define Mn   (Bn*Nn)      // 40960 rows
#define K3n  1536
#define NPn  22           // padded sequence rows
#define BKn  32

typedef __attribute__((ext_vector_type(4))) float  floatx4;
typedef __attribute__((ext_vector_type(8))) __bf16 bf16x8;
typedef __attribute__((ext_vector_type(4))) __bf16 bf16x4;

// -------- async global->LDS, 16B per lane; LDS base must be wave-uniform ----
__device__ __forceinline__ void gload_lds16(const void* g, void* l) {
  __builtin_amdgcn_global_load_lds(
      (const __attribute__((address_space(1))) void*)g,
      (__attribute__((address_space(3))) void*)l, 16, 0, 0);
}

// ============================ prep kernels ==================================
// Xpad[b][0]=0, Xpad[b][n]=bf16(x[b][n-1]), Xpad[b][21]=0
__global__ void k_prep_xpad(const float* __restrict__ x, __bf16* __restrict__ xpad) {
  int idx = blockIdx.x * 256 + threadIdx.x;      // over B*22*64 chunks of 8
  int d8 = idx & 63;
  int t  = idx >> 6;                              // b*22 + n
  if (t >= Bn * NPn) return;
  int n = t % NPn;
  int b = t / NPn;
  bf16x8 v;
  if (n == 0 || n == NPn - 1) {
#pragma unroll
    for (int e = 0; e < 8; ++e) v[e] = (__bf16)0.f;
  } else {
    const float4 x0 = *(const float4*)(x + (size_t)((b * Nn + n - 1) * Dn) + d8 * 8);
    const float4 x1 = *(const float4*)(x + (size_t)((b * Nn + n - 1) * Dn) + d8 * 8 + 4);
    v[0] = (__bf16)x0.x; v[1] = (__bf16)x0.y; v[2] = (__bf16)x0.z; v[3] = (__bf16)x0.w;
    v[4] = (__bf16)x1.x; v[5] = (__bf16)x1.y; v[6] = (__bf16)x1.z; v[7] = (__bf16)x1.w;
  }
  *(bf16x8*)(xpad + (size_t)t * Dn + d8 * 8) = v;
}

// wctf: MFMA-fragment-ordered conv weights.
// Element (((kt*96 + cb)*64 + l)*8 + e) = B^T[col][k] where
//   col = cb*16 + (l&15), k = kt*32 + (l>>4)*8 + e,
//   B^T[j][kk] = Wseg[o][i][kker], j = seg*512+o, kk = kker*512+i.
__global__ void k_prep_wctf(const float* __restrict__ Wq, const float* __restrict__ Wk,
                            const float* __restrict__ Wv, __bf16* __restrict__ wctf) {
  int t = blockIdx.x * 256 + threadIdx.x;        // 0 .. 48*96*64-1
  if (t >= 48 * 96 * 64) return;
  int l  = t & 63;
  int cb = (t >> 6) % 96;
  int kt = t / (96 * 64);
  int col = cb * 16 + (l & 15);
  int k   = kt * 32 + (l >> 4) * 8;
  int seg = col >> 9, o = col & 511;
  int kker = k >> 9, i = k & 511;
  const float* W = (seg == 0) ? Wq : ((seg == 1) ? Wk : Wv);
  const float* s = W + ((size_t)o * 512 + i) * 3 + kker;
  bf16x8 v;
#pragma unroll
  for (int e = 0; e < 8; ++e) v[e] = (__bf16)s[e * 3];
  *(bf16x8*)(wctf + (size_t)t * 8) = v;
}

// wotf: fragment-ordered Wo^T. Element (((kt*32+cb)*64+l)*8+e) = Wo[k][col],
// col = cb*16+(l&15), k = kt*32+(l>>4)*8+e.
__global__ void k_prep_wotf(const float* __restrict__ Wo, __bf16* __restrict__ wotf) {
  int t = blockIdx.x * 256 + threadIdx.x;        // 0 .. 16*32*64-1
  if (t >= 16 * 32 * 64) return;
  int l  = t & 63;
  int cb = (t >> 6) & 31;
  int kt = t / (32 * 64);
  int col = cb * 16 + (l & 15);
  int k   = kt * 32 + (l >> 4) * 8;
  const float* s = Wo + (size_t)k * 512 + col;
  bf16x8 v;
#pragma unroll
  for (int e = 0; e < 8; ++e) v[e] = (__bf16)s[(size_t)e * 512];
  *(bf16x8*)(wotf + (size_t)t * 8) = v;
}

// WqfT[dq][d] = Wqf[d][dq]
__global__ void k_prep_wqft(const float* __restrict__ Wqf, __bf16* __restrict__ wqft) {
  int idx = blockIdx.x * 256 + threadIdx.x;
  if (idx >= Dn * 64) return;
  int d = idx & 511, dq = idx >> 9;
  wqft[idx] = (__bf16)Wqf[d * 64 + dq];
}

// bias[h][i][j] = rel_table[i-j+19][h] + alpha*gsb[h][i][j] + bqp[h]
__global__ void k_bias(const float* __restrict__ rel, const float* __restrict__ gsb,
                       const float* __restrict__ alpha, const float* __restrict__ bqp,
                       float* __restrict__ bias) {
  int idx = blockIdx.x * 256 + threadIdx.x;
  if (idx >= Hn * Nn * Nn) return;
  int j = idx % Nn;
  int i = (idx / Nn) % Nn;
  int h = idx / (Nn * Nn);
  bias[idx] = rel[(i - j + Nn - 1) * Hn + h] + alpha[0] * gsb[idx] + bqp[h];
}

// ===== shared-A / private-B GEMM step (128x512 tile, 8 waves) ===============
// Wave tile = 128 rows x 64 cols (acc[8][4]); every wave reads ALL rows from
// a SHARED 8KB LDS A buffer (staged once per block: 1 gload_lds/thread/step,
// double-buffered) and streams its own 4 B fragments global->reg from the
// fragment-ordered weight buffer (L2-hot, coalesced 1KB/frag), double-buffered
// one step ahead. L2 traffic: 40KB/block-step for 256 MFMAs = 160 B/MFMA
// (2.4x less than v4). Only barrier-coupled op is the tiny A stage, issued a
// full step early. Requires in scope: gA, gW, lsA, dA, fAo[8], acc[8][4].
#define LOADB4(DST, ADV) do {                                          \
    _Pragma("unroll")                                                  \
    for (int _tc = 0; _tc < 4; ++_tc)                                  \
      DST[_tc] = *(const bf16x8*)(gW + _tc * 512);                     \
    gW += (ADV);                                                       \
  } while (0)

#define QSTEP(CB, NB, CUR, NXT, DOSTAGE, ADV) do {                     \
    if (DOSTAGE) {                                                     \
      gload_lds16(gA, lsA + (NB) * 4096 + dA); gA += BKn;              \
      LOADB4(NXT, ADV);                                                \
    }                                                                  \
    const __bf16* _L = lsA + (CB) * 4096;                              \
    bf16x8 _a0 = *(const bf16x8*)(_L + fAo[0]);                        \
    bf16x8 _a1 = *(const bf16x8*)(_L + fAo[1]);                        \
    bf16x8 _a2 = *(const bf16x8*)(_L + fAo[2]);                        \
    bf16x8 _a3 = *(const bf16x8*)(_L + fAo[3]);                        \
    bf16x8 _a4 = *(const bf16x8*)(_L + fAo[4]);                        \
    bf16x8 _a5 = *(const bf16x8*)(_L + fAo[5]);                        \
    bf16x8 _a6 = *(const bf16x8*)(_L + fAo[6]);                        \
    bf16x8 _a7 = *(const bf16x8*)(_L + fAo[7]);                        \
    __builtin_amdgcn_s_setprio(1);                                     \
    _Pragma("unroll")                                                  \
    for (int _tc = 0; _tc < 4; ++_tc) {                                \
      acc[0][_tc] = __builtin_amdgcn_mfma_f32_16x16x32_bf16(_a0, CUR[_tc], acc[0][_tc], 0, 0, 0); \
      acc[1][_tc] = __builtin_amdgcn_mfma_f32_16x16x32_bf16(_a1, CUR[_tc], acc[1][_tc], 0, 0, 0); \
      acc[2][_tc] = __builtin_amdgcn_mfma_f32_16x16x32_bf16(_a2, CUR[_tc], acc[2][_tc], 0, 0, 0); \
      acc[3][_tc] = __builtin_amdgcn_mfma_f32_16x16x32_bf16(_a3, CUR[_tc], acc[3][_tc], 0, 0, 0); \
      acc[4][_tc] = __builtin_amdgcn_mfma_f32_16x16x32_bf16(_a4, CUR[_tc], acc[4][_tc], 0, 0, 0); \
      acc[5][_tc] = __builtin_amdgcn_mfma_f32_16x16x32_bf16(_a5, CUR[_tc], acc[5][_tc], 0, 0, 0); \
      acc[6][_tc] = __builtin_amdgcn_mfma_f32_16x16x32_bf16(_a6, CUR[_tc], acc[6][_tc], 0, 0, 0); \
      acc[7][_tc] = __builtin_amdgcn_mfma_f32_16x16x32_bf16(_a7, CUR[_tc], acc[7][_tc], 0, 0, 0); \
    }                                                                  \
    __builtin_amdgcn_s_setprio(0);                                     \
    asm volatile("s_waitcnt vmcnt(0) lgkmcnt(0)\n\ts_barrier" ::: "memory"); \
  } while (0)

// ================= QKV conv-GEMM + LayerNorm + residual =====================
// Grid 960 = 8 XCDs x {3 segs x 40 m-tiles interleaved} (A-tile L2-hot across
// the 3 segs). 512 thr = 8 waves, wave wv owns cols wv*64..wv*64+63.
__global__ __launch_bounds__(512, 2)
void k_qkv(const __bf16* __restrict__ xpad, const __bf16* __restrict__ wctf,
           const float* __restrict__ gq_g, const float* __restrict__ gq_b,
           const float* __restrict__ gk_g, const float* __restrict__ gk_b,
           const float* __restrict__ gv_g, const float* __restrict__ gv_b,
           __bf16* __restrict__ qkv) {
  __shared__ __bf16 lsA[2 * 4096];     // 2 x 8KB shared A (128x32)

  const int tid  = threadIdx.x;
  const int wv   = tid >> 6;           // wave 0..7 = col group
  const int lane = tid & 63;
  const int quad = lane >> 4;
  const int l15  = lane & 15;

  // XCD swizzle: segs of one m-tile adjacent on same XCD
  const int bid   = blockIdx.x;
  const int xcd   = bid & 7;
  const int local = bid >> 3;          // 0..119
  const int seg   = local % 3;
  const int mt    = xcd * 40 + local / 3;   // 0..319
  const int m0    = mt * 128;

  // --- A staging source: 1 chunk per thread (512 chunks = 128 rows x 32k) ---
  const __bf16* gA;
  {
    int c   = tid;
    int row = c >> 2;
    int rk  = (c & 3) ^ ((row >> 1) & 3);
    int grow = m0 + row;
    int b = grow / Nn, n = grow - b * Nn;
    gA = xpad + (size_t)(b * NPn + n) * Dn + rk * 8;  // covers x rows n-1..n+1
  }
  const int dA = wv * 512;             // wave-uniform LDS dest (elements)

  // --- B fragment stream: cb = seg*32 + wv*4 + tc ---
  const __bf16* gW = wctf + ((size_t)(seg * 32 + wv * 4) * 512) + lane * 8;

  // --- A fragment LDS element-offsets (shared buffer) ---
  int fAo[8];
#pragma unroll
  for (int mi = 0; mi < 8; ++mi) {
    int row = mi * 16 + l15;
    fAo[mi] = row * BKn + (quad ^ ((row >> 1) & 3)) * 8;
  }

  floatx4 acc[8][4];
  const floatx4 zero = {0.f, 0.f, 0.f, 0.f};
#pragma unroll
  for (int i = 0; i < 8; ++i)
#pragma unroll
    for (int j = 0; j < 4; ++j) acc[i][j] = zero;

  bf16x8 bA[4], bB[4];

  // prologue: stage A(0), load B(0)
  gload_lds16(gA, lsA + dA); gA += BKn;
  LOADB4(bA, 49152);
  asm volatile("s_waitcnt vmcnt(0)\n\ts_barrier" ::: "memory");

#pragma unroll 1
  for (int it = 0; it < 24; ++it) {            // 48 K-steps
    QSTEP(0, 1, bA, bB, (2 * it)     < 47, 49152);
    QSTEP(1, 0, bB, bA, (2 * it + 1) < 47, 49152);
  }

  // --- fused LayerNorm + residual epilogue (red arrays overlay lsA) ---
  float* red1 = (float*)lsA;           // 128 rows x 8 waves = 4KB
  float* red2 = red1 + 1024;
#pragma unroll
  for (int mi = 0; mi < 8; ++mi)
#pragma unroll
    for (int r = 0; r < 4; ++r) {
      float a = 0.f, b2 = 0.f;
#pragma unroll
      for (int tc = 0; tc < 4; ++tc) { float v = acc[mi][tc][r]; a += v; b2 += v * v; }
#pragma unroll
      for (int off = 1; off < 16; off <<= 1) {
        a  += __shfl_xor(a, off, 64);
        b2 += __shfl_xor(b2, off, 64);
      }
      if (l15 == 0) {
        int row = mi * 16 + quad * 4 + r;
        red1[row * 8 + wv] = a;
        red2[row * 8 + wv] = b2;
      }
    }
  __syncthreads();

  const float* gg = (seg == 0) ? gq_g : ((seg == 1) ? gk_g : gv_g);
  const float* bb = (seg == 0) ? gq_b : ((seg == 1) ? gk_b : gv_b);
#pragma unroll
  for (int mi = 0; mi < 8; ++mi)
#pragma unroll
    for (int r = 0; r < 4; ++r) {
      int row = mi * 16 + quad * 4 + r;
      float su = 0.f, sq = 0.f;
#pragma unroll
      for (int w = 0; w < 8; ++w) { su += red1[row * 8 + w]; sq += red2[row * 8 + w]; }
      float mn = su * (1.f / 512.f);
      float vv = sq * (1.f / 512.f) - mn * mn;
      float rstd = rsqrtf(vv + 1e-5f);
      int grow = m0 + row;
      int b = grow / Nn, n2 = grow - b * Nn;
      const __bf16* xr = xpad + (size_t)(b * NPn + n2 + 1) * Dn;  // bf16 residual
#pragma unroll
      for (int tc = 0; tc < 4; ++tc) {
        int col = wv * 64 + tc * 16 + l15;
        float val = (acc[mi][tc][r] - mn) * rstd * gg[col] + bb[col] + (float)xr[col];
        qkv[(size_t)grow * K3n + seg * 512 + col] = (__bf16)val;
      }
    }
}

// ======== qfp = tanh(x @ Wqf + bqf) @ Wqp  (fused, fp32 out) ================
__global__ __launch_bounds__(256)
void k_qfqp(const __bf16* __restrict__ xpad, const __bf16* __restrict__ wqft,
            const float* __restrict__ bqf, const float* __restrict__ wqp,
            float* __restrict__ qfp) {
  __shared__ __bf16 sA[64 * BKn];
  __shared__ __bf16 sB[64 * BKn];
  __shared__ float lWqpT[8 * 64];   // [h][col]
  const int tid  = threadIdx.x;
  const int wave = tid >> 6;
  const int lane = tid & 63;
  const int quad = lane >> 4;
  const int l15  = lane & 15;
  const int m0   = blockIdx.x * 64;

#pragma unroll
  for (int t = tid; t < 512; t += 256) {
    int col = t & 63, h = t >> 6;
    lWqpT[t] = wqp[col * 8 + h];
  }

  int c = wave * 64 + lane;
  int rowc = c >> 2;
  int rk   = (c & 3) ^ ((rowc >> 1) & 3);
  int grow = m0 + rowc;
  int b = grow / Nn, n = grow - b * Nn;
  const __bf16* gA = xpad + (size_t)(b * NPn + n + 1) * Dn + rk * 8;  // x[b][n]
  const __bf16* gB = wqft + (size_t)rowc * Dn + rk * 8;

  int frow = wave * 16 + l15;
  const __bf16* fA = sA + frow * BKn + (quad ^ ((frow >> 1) & 3)) * 8;
  const __bf16* fB[4];
#pragma unroll
  for (int tc = 0; tc < 4; ++tc) {
    int col = tc * 16 + l15;
    fB[tc] = sB + col * BKn + (quad ^ ((col >> 1) & 3)) * 8;
  }

  const floatx4 zero = {0.f, 0.f, 0.f, 0.f};
  floatx4 acc[4] = {zero, zero, zero, zero};

  for (int kt = 0; kt < Dn / BKn; ++kt) {
    gload_lds16(gA, sA + wave * 512);
    gload_lds16(gB, sB + wave * 512);
    __syncthreads();
    bf16x8 a = *(const bf16x8*)fA;
#pragma unroll
    for (int tc = 0; tc < 4; ++tc)
      acc[tc] = __builtin_amdgcn_mfma_f32_16x16x32_bf16(a, *(const bf16x8*)fB[tc], acc[tc], 0, 0, 0);
    __syncthreads();
    gA += BKn; gB += BKn;
  }

  float part[4][8];
#pragma unroll
  for (int r = 0; r < 4; ++r)
#pragma unroll
    for (int h = 0; h < 8; ++h) part[r][h] = 0.f;
#pragma unroll
  for (int tc = 0; tc < 4; ++tc) {
    int col = tc * 16 + l15;
    float bq = bqf[col];
#pragma unroll
    for (int r = 0; r < 4; ++r) {
      float t = tanhf(acc[tc][r] + bq);
#pragma unroll
      for (int h = 0; h < 8; ++h) part[r][h] += t * lWqpT[h * 64 + col];
    }
  }
#pragma unroll
  for (int off = 1; off < 16; off <<= 1)
#pragma unroll
    for (int r = 0; r < 4; ++r)
#pragma unroll
      for (int h = 0; h < 8; ++h) part[r][h] += __shfl_xor(part[r][h], off, 64);
  if (l15 == 0) {
#pragma unroll
    for (int r = 0; r < 4; ++r) {
      int row = wave * 16 + quad * 4 + r;
#pragma unroll
      for (int h = 0; h < 8; ++h)
        qfp[(size_t)(m0 + row) * 8 + h] = part[r][h];
    }
  }
}

// =========================== attention (fp32) ===============================
__global__ __launch_bounds__(256)
void k_attn(const __bf16* __restrict__ qkv, const float* __restrict__ qfp,
            const float* __restrict__ bias, __bf16* __restrict__ aout) {
  __shared__ float sq[4][Nn * 64];
  __shared__ float sk[4][Nn * 68];
  __shared__ float sv[4][Nn * 68];
  __shared__ float sp[4][Nn * Nn];
  __shared__ float sf[4][Nn];
  const int tid  = threadIdx.x;
  const int w    = tid >> 6;
  const int lane = tid & 63;
  const int p0 = blockIdx.x * 4 + w;
  const int b = p0 >> 3, h = p0 & 7;
  const __bf16* qb = qkv + (size_t)b * Nn * K3n + h * 64;

  for (int idx = lane; idx < 160; idx += 64) {
    int n = idx >> 3, c = (idx & 7) * 8;
    bf16x8 qv = *(const bf16x8*)(qb + (size_t)n * K3n + c);
    bf16x8 kv = *(const bf16x8*)(qb + (size_t)n * K3n + 512 + c);
    bf16x8 vv = *(const bf16x8*)(qb + (size_t)n * K3n + 1024 + c);
#pragma unroll
    for (int e = 0; e < 8; ++e) {
      sq[w][n * 64 + c + e] = (float)qv[e];
      sk[w][n * 68 + c + e] = (float)kv[e];
      sv[w][n * 68 + c + e] = (float)vv[e];
    }
  }
  if (lane < Nn) sf[w][lane] = qfp[(size_t)(b * Nn + lane) * 8 + h];
  __syncthreads();

  const float* bh = bias + h * Nn * Nn;
  for (int p = lane; p < Nn * Nn; p += 64) {
    int i = p / Nn, j = p - i * Nn;
    const float4* q4 = (const float4*)&sq[w][i * 64];
    const float4* k4 = (const float4*)&sk[w][j * 68];
    float s = 0.f;
#pragma unroll
    for (int d4 = 0; d4 < 16; ++d4) {
      float4 qa = q4[d4], ka = k4[d4];
      s += qa.x * ka.x + qa.y * ka.y + qa.z * ka.z + qa.w * ka.w;
    }
    sp[w][p] = s * 0.125f + bh[p] + sf[w][i] - sf[w][j];
  }
  __syncthreads();
  if (lane < Nn) {
    int i = lane;
    float* row = &sp[w][i * Nn];
    float mx = row[0];
    for (int j = 1; j < Nn; ++j) mx = fmaxf(mx, row[j]);
    float sum = 0.f;
    for (int j = 0; j < Nn; ++j) { float e = __expf(row[j] - mx); row[j] = e; sum += e; }
    float inv = 1.f / sum;
    for (int j = 0; j < Nn; ++j) row[j] *= inv;
  }
  __syncthreads();
  for (int i = 0; i < Nn; ++i) {
    float a = 0.f;
#pragma unroll
    for (int j = 0; j < Nn; ++j) a += sp[w][i * Nn + j] * sv[w][j * 68 + lane];
    aout[(size_t)(b * Nn + i) * Dn + h * 64 + lane] = (__bf16)a;
  }
}

// ==================== out = attn_out @ Wo + bo (fp32 out) ===================
// Same shared-A / private-B structure. K=512 -> 16 steps. Grid 320 = 8 x 40.
__global__ __launch_bounds__(512, 2)
void k_oproj(const __bf16* __restrict__ aout, const __bf16* __restrict__ wotf,
             const float* __restrict__ bo, float* __restrict__ out) {
  __shared__ __bf16 lsA[2 * 4096];
  const int tid  = threadIdx.x;
  const int wv   = tid >> 6;
  const int lane = tid & 63;
  const int quad = lane >> 4;
  const int l15  = lane & 15;

  const int bid = blockIdx.x;
  const int m0  = ((bid & 7) * 40 + (bid >> 3)) * 128;

  const __bf16* gA;
  {
    int c   = tid;
    int row = c >> 2;
    int rk  = (c & 3) ^ ((row >> 1) & 3);
    gA = aout + (size_t)(m0 + row) * Dn + rk * 8;
  }
  const int dA = wv * 512;
  const __bf16* gW = wotf + ((size_t)(wv * 4) * 512) + lane * 8;

  int fAo[8];
#pragma unroll
  for (int mi = 0; mi < 8; ++mi) {
    int row = mi * 16 + l15;
    fAo[mi] = row * BKn + (quad ^ ((row >> 1) & 3)) * 8;
  }

  floatx4 acc[8][4];
  const floatx4 zero = {0.f, 0.f, 0.f, 0.f};
#pragma unroll
  for (int i = 0; i < 8; ++i)
#pragma unroll
    for (int j = 0; j < 4; ++j) acc[i][j] = zero;

  bf16x8 bA[4], bB[4];

  gload_lds16(gA, lsA + dA); gA += BKn;
  LOADB4(bA, 16384);
  asm volatile("s_waitcnt vmcnt(0)\n\ts_barrier" ::: "memory");

#pragma unroll 1
  for (int it = 0; it < 8; ++it) {             // 16 K-steps
    QSTEP(0, 1, bA, bB, (2 * it)     < 15, 16384);
    QSTEP(1, 0, bB, bA, (2 * it + 1) < 15, 16384);
  }

#pragma unroll
  for (int mi = 0; mi < 8; ++mi)
#pragma unroll
    for (int r = 0; r < 4; ++r) {
      int row = mi * 16 + quad * 4 + r;
#pragma unroll
      for (int tc = 0; tc < 4; ++tc) {
        int col = wv * 64 + tc * 16 + l15;
        out[(size_t)(m0 + row) * Dn + col] = acc[mi][tc][r] + bo[col];
      }
    }
}

// ============================ workspace layout ==============================
static const size_t OFF_XPAD = 0;                     // 46,137,344 B (bf16 Xpad)
static const size_t OFF_WCT  = 46137344;              //  4,718,592 B (wctf)
static const size_t OFF_WOT  = 50855936;              //    524,288 B (wotf)
static const size_t OFF_WQFT = 51380224;              //     65,536 B
static const size_t OFF_QKV  = 51445760;              // 125,829,120 B
static const size_t OFF_QFP  = 177274880;             //  1,310,720 B
static const size_t OFF_BIAS = 178585600;             //     12,800 B
static const size_t OFF_AOUT = 0;                     // overlays Xpad (dead after k_qfqp/k_qkv)

extern "C" void kernel_launch(void* const* d_in, const int* in_sizes, int n_in,
                              void* d_out, int out_size, void* d_ws, size_t ws_size,
                              hipStream_t stream) {
  (void)in_sizes; (void)n_in; (void)out_size; (void)ws_size;
  const float* x     = (const float*)d_in[0];
  const float* Wq    = (const float*)d_in[1];
  const float* Wk    = (const float*)d_in[2];
  const float* Wv    = (const float*)d_in[3];
  const float* gq_g  = (const float*)d_in[4];
  const float* gq_b  = (const float*)d_in[5];
  const float* gk_g  = (const float*)d_in[6];
  const float* gk_b  = (const float*)d_in[7];
  const float* gv_g  = (const float*)d_in[8];
  const float* gv_b  = (const float*)d_in[9];
  const float* rel   = (const float*)d_in[10];
  const float* gsb   = (const float*)d_in[11];
  const float* alpha = (const float*)d_in[12];
  const float* Wqf   = (const float*)d_in[13];
  const float* bqf   = (const float*)d_in[14];
  const float* Wqp   = (const float*)d_in[15];
  const float* bqp   = (const float*)d_in[16];
  const float* Wo    = (const float*)d_in[17];
  const float* bo    = (const float*)d_in[18];
  float* out = (float*)d_out;
  char* ws = (char*)d_ws;

  __bf16* xpad = (__bf16*)(ws + OFF_XPAD);
  __bf16* wctf = (__bf16*)(ws + OFF_WCT);
  __bf16* wotf = (__bf16*)(ws + OFF_WOT);
  __bf16* wqft = (__bf16*)(ws + OFF_WQFT);
  __bf16* qkv  = (__bf16*)(ws + OFF_QKV);
  float*  qfp  = (float*)(ws + OFF_QFP);
  float*  bias = (float*)(ws + OFF_BIAS);
  __bf16* aout = (__bf16*)(ws + OFF_AOUT);

  k_prep_xpad<<<(Bn * NPn * (Dn / 8) + 255) / 256, 256, 0, stream>>>(x, xpad);
  k_prep_wctf<<<(48 * 96 * 64 + 255) / 256, 256, 0, stream>>>(Wq, Wk, Wv, wctf);
  k_prep_wotf<<<(16 * 32 * 64 + 255) / 256, 256, 0, stream>>>(Wo, wotf);
  k_prep_wqft<<<(Dn * 64 + 255) / 256, 256, 0, stream>>>(Wqf, wqft);
  k_bias     <<<(Hn * Nn * Nn + 255) / 256, 256, 0, stream>>>(rel, gsb, alpha, bqp, bias);

  k_qkv <<<Mn / 128 * 3, 512, 0, stream>>>(xpad, wctf, gq_g, gq_b, gk_g, gk_b, gv_g, gv_b, qkv);
  k_qfqp<<<Mn / 64, 256, 0, stream>>>(xpad, wqft, bqf, Wqp, qfp);
  k_attn<<<(Bn * Hn) / 4, 256, 0, stream>>>(qkv, qfp, bias, aout);
  k_oproj<<<Mn / 128, 512, 0, stream>>>(aout, wotf, bo, out);
}

// Round 6
// 571.289 us; speedup vs baseline: 1.0079x; 1.0079x over previous
//
#include <hip/hip_runtime.h>
#include <stdint.h>

#define Bn   2048
#define Nn   20
#define Dn   512
#define Hn   8
#define Mn   (Bn*Nn)      // 40960 rows
#define K3n  1536
#define NPn  22           // padded sequence rows
#define BKn  32

typedef __attribute__((ext_vector_type(4))) float  floatx4;
typedef __attribute__((ext_vector_type(8))) __bf16 bf16x8;
typedef __attribute__((ext_vector_type(4))) __bf16 bf16x4;

// -------- async global->LDS, 16B per lane; LDS base must be wave-uniform ----
__device__ __forceinline__ void gload_lds16(const void* g, void* l) {
  __builtin_amdgcn_global_load_lds(
      (const __attribute__((address_space(1))) void*)g,
      (__attribute__((address_space(3))) void*)l, 16, 0, 0);
}

// ============================ prep kernels ==================================
// Xpad[b][0]=0, Xpad[b][n]=bf16(x[b][n-1]), Xpad[b][21]=0
__global__ void k_prep_xpad(const float* __restrict__ x, __bf16* __restrict__ xpad) {
  int idx = blockIdx.x * 256 + threadIdx.x;      // over B*22*64 chunks of 8
  int d8 = idx & 63;
  int t  = idx >> 6;                              // b*22 + n
  if (t >= Bn * NPn) return;
  int n = t % NPn;
  int b = t / NPn;
  bf16x8 v;
  if (n == 0 || n == NPn - 1) {
#pragma unroll
    for (int e = 0; e < 8; ++e) v[e] = (__bf16)0.f;
  } else {
    const float4 x0 = *(const float4*)(x + (size_t)((b * Nn + n - 1) * Dn) + d8 * 8);
    const float4 x1 = *(const float4*)(x + (size_t)((b * Nn + n - 1) * Dn) + d8 * 8 + 4);
    v[0] = (__bf16)x0.x; v[1] = (__bf16)x0.y; v[2] = (__bf16)x0.z; v[3] = (__bf16)x0.w;
    v[4] = (__bf16)x1.x; v[5] = (__bf16)x1.y; v[6] = (__bf16)x1.z; v[7] = (__bf16)x1.w;
  }
  *(bf16x8*)(xpad + (size_t)t * Dn + d8 * 8) = v;
}

// wctf: MFMA-fragment-ordered conv weights.
// Element (((kt*96 + cb)*64 + l)*8 + e) = B^T[col][k] where
//   col = cb*16 + (l&15), k = kt*32 + (l>>4)*8 + e,
//   B^T[j][kk] = Wseg[o][i][kker], j = seg*512+o, kk = kker*512+i.
__global__ void k_prep_wctf(const float* __restrict__ Wq, const float* __restrict__ Wk,
                            const float* __restrict__ Wv, __bf16* __restrict__ wctf) {
  int t = blockIdx.x * 256 + threadIdx.x;        // 0 .. 48*96*64-1
  if (t >= 48 * 96 * 64) return;
  int l  = t & 63;
  int cb = (t >> 6) % 96;
  int kt = t / (96 * 64);
  int col = cb * 16 + (l & 15);
  int k   = kt * 32 + (l >> 4) * 8;
  int seg = col >> 9, o = col & 511;
  int kker = k >> 9, i = k & 511;
  const float* W = (seg == 0) ? Wq : ((seg == 1) ? Wk : Wv);
  const float* s = W + ((size_t)o * 512 + i) * 3 + kker;
  bf16x8 v;
#pragma unroll
  for (int e = 0; e < 8; ++e) v[e] = (__bf16)s[e * 3];
  *(bf16x8*)(wctf + (size_t)t * 8) = v;
}

// wotf: fragment-ordered Wo^T. Element (((kt*32+cb)*64+l)*8+e) = Wo[k][col],
// col = cb*16+(l&15), k = kt*32+(l>>4)*8+e.
__global__ void k_prep_wotf(const float* __restrict__ Wo, __bf16* __restrict__ wotf) {
  int t = blockIdx.x * 256 + threadIdx.x;        // 0 .. 16*32*64-1
  if (t >= 16 * 32 * 64) return;
  int l  = t & 63;
  int cb = (t >> 6) & 31;
  int kt = t / (32 * 64);
  int col = cb * 16 + (l & 15);
  int k   = kt * 32 + (l >> 4) * 8;
  const float* s = Wo + (size_t)k * 512 + col;
  bf16x8 v;
#pragma unroll
  for (int e = 0; e < 8; ++e) v[e] = (__bf16)s[(size_t)e * 512];
  *(bf16x8*)(wotf + (size_t)t * 8) = v;
}

// WqfT[dq][d] = Wqf[d][dq]
__global__ void k_prep_wqft(const float* __restrict__ Wqf, __bf16* __restrict__ wqft) {
  int idx = blockIdx.x * 256 + threadIdx.x;
  if (idx >= Dn * 64) return;
  int d = idx & 511, dq = idx >> 9;
  wqft[idx] = (__bf16)Wqf[d * 64 + dq];
}

// bias[h][i][j] = rel_table[i-j+19][h] + alpha*gsb[h][i][j] + bqp[h]
__global__ void k_bias(const float* __restrict__ rel, const float* __restrict__ gsb,
                       const float* __restrict__ alpha, const float* __restrict__ bqp,
                       float* __restrict__ bias) {
  int idx = blockIdx.x * 256 + threadIdx.x;
  if (idx >= Hn * Nn * Nn) return;
  int j = idx % Nn;
  int i = (idx / Nn) % Nn;
  int h = idx / (Nn * Nn);
  bias[idx] = rel[(i - j + Nn - 1) * Hn + h] + alpha[0] * gsb[idx] + bqp[h];
}

// ===== shared-A / private-B GEMM step (128x512 tile, 8 waves) ===============
// Wave tile = 128 rows x 64 cols (acc[8][4]); every wave reads ALL rows from
// a SHARED 8KB LDS A buffer (staged once per block, double-buffered) and
// streams its own 4 B fragments global->reg (fragment-ordered, L2-hot,
// coalesced 1KB/frag), double-buffered one step ahead. 40KB L2 traffic per
// 256-MFMA step = 33 B/cy/CU, under the ~56 B/cy L2 budget -> MFMA-bound.
// T4 counted wait: the A-stage gload_lds is issued FIRST, B-loads after;
// vmcnt retires in issue order, so vmcnt(4) at step end waits ONLY for the
// A-stage and leaves the 4 B prefetches in flight across the barrier (never
// drain to 0 in the main loop). lgkmcnt(0) keeps buffer CB read-complete
// before t+1 overwrites it.
#define LOADB4(DST, ADV) do {                                          \
    _Pragma("unroll")                                                  \
    for (int _tc = 0; _tc < 4; ++_tc)                                  \
      DST[_tc] = *(const bf16x8*)(gW + _tc * 512);                     \
    gW += (ADV);                                                       \
  } while (0)

#define QSTEP(CB, NB, CUR, NXT, DOSTAGE, ADV, VMS) do {                \
    if (DOSTAGE) {                                                     \
      gload_lds16(gA, lsA + (NB) * 4096 + dA); gA += BKn;              \
      LOADB4(NXT, ADV);                                                \
    }                                                                  \
    const __bf16* _L = lsA + (CB) * 4096;                              \
    bf16x8 _a0 = *(const bf16x8*)(_L + fAo[0]);                        \
    bf16x8 _a1 = *(const bf16x8*)(_L + fAo[1]);                        \
    bf16x8 _a2 = *(const bf16x8*)(_L + fAo[2]);                        \
    bf16x8 _a3 = *(const bf16x8*)(_L + fAo[3]);                        \
    bf16x8 _a4 = *(const bf16x8*)(_L + fAo[4]);                        \
    bf16x8 _a5 = *(const bf16x8*)(_L + fAo[5]);                        \
    bf16x8 _a6 = *(const bf16x8*)(_L + fAo[6]);                        \
    bf16x8 _a7 = *(const bf16x8*)(_L + fAo[7]);                        \
    __builtin_amdgcn_s_setprio(1);                                     \
    _Pragma("unroll")                                                  \
    for (int _tc = 0; _tc < 4; ++_tc) {                                \
      acc[0][_tc] = __builtin_amdgcn_mfma_f32_16x16x32_bf16(_a0, CUR[_tc], acc[0][_tc], 0, 0, 0); \
      acc[1][_tc] = __builtin_amdgcn_mfma_f32_16x16x32_bf16(_a1, CUR[_tc], acc[1][_tc], 0, 0, 0); \
      acc[2][_tc] = __builtin_amdgcn_mfma_f32_16x16x32_bf16(_a2, CUR[_tc], acc[2][_tc], 0, 0, 0); \
      acc[3][_tc] = __builtin_amdgcn_mfma_f32_16x16x32_bf16(_a3, CUR[_tc], acc[3][_tc], 0, 0, 0); \
      acc[4][_tc] = __builtin_amdgcn_mfma_f32_16x16x32_bf16(_a4, CUR[_tc], acc[4][_tc], 0, 0, 0); \
      acc[5][_tc] = __builtin_amdgcn_mfma_f32_16x16x32_bf16(_a5, CUR[_tc], acc[5][_tc], 0, 0, 0); \
      acc[6][_tc] = __builtin_amdgcn_mfma_f32_16x16x32_bf16(_a6, CUR[_tc], acc[6][_tc], 0, 0, 0); \
      acc[7][_tc] = __builtin_amdgcn_mfma_f32_16x16x32_bf16(_a7, CUR[_tc], acc[7][_tc], 0, 0, 0); \
    }                                                                  \
    __builtin_amdgcn_s_setprio(0);                                     \
    asm volatile("s_waitcnt vmcnt(" VMS ") lgkmcnt(0)\n\ts_barrier" ::: "memory"); \
  } while (0)

// ================= QKV conv-GEMM + LayerNorm + residual =====================
// Grid 960 = 8 XCDs x {3 segs x 40 m-tiles interleaved} (A-tile L2-hot across
// the 3 segs). 512 thr = 8 waves, wave wv owns cols wv*64..wv*64+63.
__global__ __launch_bounds__(512, 2)
void k_qkv(const __bf16* __restrict__ xpad, const __bf16* __restrict__ wctf,
           const float* __restrict__ gq_g, const float* __restrict__ gq_b,
           const float* __restrict__ gk_g, const float* __restrict__ gk_b,
           const float* __restrict__ gv_g, const float* __restrict__ gv_b,
           __bf16* __restrict__ qkv) {
  __shared__ __bf16 lsA[2 * 4096];     // 2 x 8KB shared A (128x32)

  const int tid  = threadIdx.x;
  const int wv   = tid >> 6;           // wave 0..7 = col group
  const int lane = tid & 63;
  const int quad = lane >> 4;
  const int l15  = lane & 15;

  // XCD swizzle: segs of one m-tile adjacent on same XCD
  const int bid   = blockIdx.x;
  const int xcd   = bid & 7;
  const int local = bid >> 3;          // 0..119
  const int seg   = local % 3;
  const int mt    = xcd * 40 + local / 3;   // 0..319
  const int m0    = mt * 128;

  // --- A staging source: 1 chunk per thread (512 chunks = 128 rows x 32k) ---
  const __bf16* gA;
  {
    int c   = tid;
    int row = c >> 2;
    int rk  = (c & 3) ^ ((row >> 1) & 3);
    int grow = m0 + row;
    int b = grow / Nn, n = grow - b * Nn;
    gA = xpad + (size_t)(b * NPn + n) * Dn + rk * 8;  // covers x rows n-1..n+1
  }
  const int dA = wv * 512;             // wave-uniform LDS dest (elements)

  // --- B fragment stream: cb = seg*32 + wv*4 + tc ---
  const __bf16* gW = wctf + ((size_t)(seg * 32 + wv * 4) * 512) + lane * 8;

  // --- A fragment LDS element-offsets (shared buffer) ---
  int fAo[8];
#pragma unroll
  for (int mi = 0; mi < 8; ++mi) {
    int row = mi * 16 + l15;
    fAo[mi] = row * BKn + (quad ^ ((row >> 1) & 3)) * 8;
  }

  floatx4 acc[8][4];
  const floatx4 zero = {0.f, 0.f, 0.f, 0.f};
#pragma unroll
  for (int i = 0; i < 8; ++i)
#pragma unroll
    for (int j = 0; j < 4; ++j) acc[i][j] = zero;

  bf16x8 bA[4], bB[4];

  // prologue: stage A(0), load B(0)
  gload_lds16(gA, lsA + dA); gA += BKn;
  LOADB4(bA, 49152);
  asm volatile("s_waitcnt vmcnt(0)\n\ts_barrier" ::: "memory");

#pragma unroll 1
  for (int it = 0; it < 23; ++it) {            // steps 0..45
    QSTEP(0, 1, bA, bB, true, 49152, "4");
    QSTEP(1, 0, bB, bA, true, 49152, "4");
  }
  QSTEP(0, 1, bA, bB, true,  49152, "4");      // step 46 (stages 47)
  QSTEP(1, 0, bB, bA, false, 49152, "0");      // step 47

  // --- fused LayerNorm + residual epilogue (red arrays overlay lsA) ---
  float* red1 = (float*)lsA;           // 128 rows x 8 waves = 4KB
  float* red2 = red1 + 1024;
#pragma unroll
  for (int mi = 0; mi < 8; ++mi)
#pragma unroll
    for (int r = 0; r < 4; ++r) {
      float a = 0.f, b2 = 0.f;
#pragma unroll
      for (int tc = 0; tc < 4; ++tc) { float v = acc[mi][tc][r]; a += v; b2 += v * v; }
#pragma unroll
      for (int off = 1; off < 16; off <<= 1) {
        a  += __shfl_xor(a, off, 64);
        b2 += __shfl_xor(b2, off, 64);
      }
      if (l15 == 0) {
        int row = mi * 16 + quad * 4 + r;
        red1[row * 8 + wv] = a;
        red2[row * 8 + wv] = b2;
      }
    }
  __syncthreads();

  const float* gg = (seg == 0) ? gq_g : ((seg == 1) ? gk_g : gv_g);
  const float* bb = (seg == 0) ? gq_b : ((seg == 1) ? gk_b : gv_b);
#pragma unroll
  for (int mi = 0; mi < 8; ++mi)
#pragma unroll
    for (int r = 0; r < 4; ++r) {
      int row = mi * 16 + quad * 4 + r;
      float su = 0.f, sq = 0.f;
#pragma unroll
      for (int w = 0; w < 8; ++w) { su += red1[row * 8 + w]; sq += red2[row * 8 + w]; }
      float mn = su * (1.f / 512.f);
      float vv = sq * (1.f / 512.f) - mn * mn;
      float rstd = rsqrtf(vv + 1e-5f);
      int grow = m0 + row;
      int b = grow / Nn, n2 = grow - b * Nn;
      const __bf16* xr = xpad + (size_t)(b * NPn + n2 + 1) * Dn;  // bf16 residual
#pragma unroll
      for (int tc = 0; tc < 4; ++tc) {
        int col = wv * 64 + tc * 16 + l15;
        float val = (acc[mi][tc][r] - mn) * rstd * gg[col] + bb[col] + (float)xr[col];
        qkv[(size_t)grow * K3n + seg * 512 + col] = (__bf16)val;
      }
    }
}

// ======== qfp = tanh(x @ Wqf + bqf) @ Wqp  (fused, fp32 out) ================
__global__ __launch_bounds__(256)
void k_qfqp(const __bf16* __restrict__ xpad, const __bf16* __restrict__ wqft,
            const float* __restrict__ bqf, const float* __restrict__ wqp,
            float* __restrict__ qfp) {
  __shared__ __bf16 sA[64 * BKn];
  __shared__ __bf16 sB[64 * BKn];
  __shared__ float lWqpT[8 * 64];   // [h][col]
  const int tid  = threadIdx.x;
  const int wave = tid >> 6;
  const int lane = tid & 63;
  const int quad = lane >> 4;
  const int l15  = lane & 15;
  const int m0   = blockIdx.x * 64;

#pragma unroll
  for (int t = tid; t < 512; t += 256) {
    int col = t & 63, h = t >> 6;
    lWqpT[t] = wqp[col * 8 + h];
  }

  int c = wave * 64 + lane;
  int rowc = c >> 2;
  int rk   = (c & 3) ^ ((rowc >> 1) & 3);
  int grow = m0 + rowc;
  int b = grow / Nn, n = grow - b * Nn;
  const __bf16* gA = xpad + (size_t)(b * NPn + n + 1) * Dn + rk * 8;  // x[b][n]
  const __bf16* gB = wqft + (size_t)rowc * Dn + rk * 8;

  int frow = wave * 16 + l15;
  const __bf16* fA = sA + frow * BKn + (quad ^ ((frow >> 1) & 3)) * 8;
  const __bf16* fB[4];
#pragma unroll
  for (int tc = 0; tc < 4; ++tc) {
    int col = tc * 16 + l15;
    fB[tc] = sB + col * BKn + (quad ^ ((col >> 1) & 3)) * 8;
  }

  const floatx4 zero = {0.f, 0.f, 0.f, 0.f};
  floatx4 acc[4] = {zero, zero, zero, zero};

  for (int kt = 0; kt < Dn / BKn; ++kt) {
    gload_lds16(gA, sA + wave * 512);
    gload_lds16(gB, sB + wave * 512);
    __syncthreads();
    bf16x8 a = *(const bf16x8*)fA;
#pragma unroll
    for (int tc = 0; tc < 4; ++tc)
      acc[tc] = __builtin_amdgcn_mfma_f32_16x16x32_bf16(a, *(const bf16x8*)fB[tc], acc[tc], 0, 0, 0);
    __syncthreads();
    gA += BKn; gB += BKn;
  }

  float part[4][8];
#pragma unroll
  for (int r = 0; r < 4; ++r)
#pragma unroll
    for (int h = 0; h < 8; ++h) part[r][h] = 0.f;
#pragma unroll
  for (int tc = 0; tc < 4; ++tc) {
    int col = tc * 16 + l15;
    float bq = bqf[col];
#pragma unroll
    for (int r = 0; r < 4; ++r) {
      float t = tanhf(acc[tc][r] + bq);
#pragma unroll
      for (int h = 0; h < 8; ++h) part[r][h] += t * lWqpT[h * 64 + col];
    }
  }
#pragma unroll
  for (int off = 1; off < 16; off <<= 1)
#pragma unroll
    for (int r = 0; r < 4; ++r)
#pragma unroll
      for (int h = 0; h < 8; ++h) part[r][h] += __shfl_xor(part[r][h], off, 64);
  if (l15 == 0) {
#pragma unroll
    for (int r = 0; r < 4; ++r) {
      int row = wave * 16 + quad * 4 + r;
#pragma unroll
      for (int h = 0; h < 8; ++h)
        qfp[(size_t)(m0 + row) * 8 + h] = part[r][h];
    }
  }
}

// =========================== attention (fp32) ===============================
__global__ __launch_bounds__(256)
void k_attn(const __bf16* __restrict__ qkv, const float* __restrict__ qfp,
            const float* __restrict__ bias, __bf16* __restrict__ aout) {
  __shared__ float sq[4][Nn * 64];
  __shared__ float sk[4][Nn * 68];
  __shared__ float sv[4][Nn * 68];
  __shared__ float sp[4][Nn * Nn];
  __shared__ float sf[4][Nn];
  const int tid  = threadIdx.x;
  const int w    = tid >> 6;
  const int lane = tid & 63;
  const int p0 = blockIdx.x * 4 + w;
  const int b = p0 >> 3, h = p0 & 7;
  const __bf16* qb = qkv + (size_t)b * Nn * K3n + h * 64;

  for (int idx = lane; idx < 160; idx += 64) {
    int n = idx >> 3, c = (idx & 7) * 8;
    bf16x8 qv = *(const bf16x8*)(qb + (size_t)n * K3n + c);
    bf16x8 kv = *(const bf16x8*)(qb + (size_t)n * K3n + 512 + c);
    bf16x8 vv = *(const bf16x8*)(qb + (size_t)n * K3n + 1024 + c);
#pragma unroll
    for (int e = 0; e < 8; ++e) {
      sq[w][n * 64 + c + e] = (float)qv[e];
      sk[w][n * 68 + c + e] = (float)kv[e];
      sv[w][n * 68 + c + e] = (float)vv[e];
    }
  }
  if (lane < Nn) sf[w][lane] = qfp[(size_t)(b * Nn + lane) * 8 + h];
  __syncthreads();

  const float* bh = bias + h * Nn * Nn;
  for (int p = lane; p < Nn * Nn; p += 64) {
    int i = p / Nn, j = p - i * Nn;
    const float4* q4 = (const float4*)&sq[w][i * 64];
    const float4* k4 = (const float4*)&sk[w][j * 68];
    float s = 0.f;
#pragma unroll
    for (int d4 = 0; d4 < 16; ++d4) {
      float4 qa = q4[d4], ka = k4[d4];
      s += qa.x * ka.x + qa.y * ka.y + qa.z * ka.z + qa.w * ka.w;
    }
    sp[w][p] = s * 0.125f + bh[p] + sf[w][i] - sf[w][j];
  }
  __syncthreads();
  if (lane < Nn) {
    int i = lane;
    float* row = &sp[w][i * Nn];
    float mx = row[0];
    for (int j = 1; j < Nn; ++j) mx = fmaxf(mx, row[j]);
    float sum = 0.f;
    for (int j = 0; j < Nn; ++j) { float e = __expf(row[j] - mx); row[j] = e; sum += e; }
    float inv = 1.f / sum;
    for (int j = 0; j < Nn; ++j) row[j] *= inv;
  }
  __syncthreads();
  for (int i = 0; i < Nn; ++i) {
    float a = 0.f;
#pragma unroll
    for (int j = 0; j < Nn; ++j) a += sp[w][i * Nn + j] * sv[w][j * 68 + lane];
    aout[(size_t)(b * Nn + i) * Dn + h * 64 + lane] = (__bf16)a;
  }
}

// ==================== out = attn_out @ Wo + bo (fp32 out) ===================
// Same shared-A / private-B structure with counted vmcnt. K=512 -> 16 steps.
__global__ __launch_bounds__(512, 2)
void k_oproj(const __bf16* __restrict__ aout, const __bf16* __restrict__ wotf,
             const float* __restrict__ bo, float* __restrict__ out) {
  __shared__ __bf16 lsA[2 * 4096];
  const int tid  = threadIdx.x;
  const int wv   = tid >> 6;
  const int lane = tid & 63;
  const int quad = lane >> 4;
  const int l15  = lane & 15;

  const int bid = blockIdx.x;
  const int m0  = ((bid & 7) * 40 + (bid >> 3)) * 128;

  const __bf16* gA;
  {
    int c   = tid;
    int row = c >> 2;
    int rk  = (c & 3) ^ ((row >> 1) & 3);
    gA = aout + (size_t)(m0 + row) * Dn + rk * 8;
  }
  const int dA = wv * 512;
  const __bf16* gW = wotf + ((size_t)(wv * 4) * 512) + lane * 8;

  int fAo[8];
#pragma unroll
  for (int mi = 0; mi < 8; ++mi) {
    int row = mi * 16 + l15;
    fAo[mi] = row * BKn + (quad ^ ((row >> 1) & 3)) * 8;
  }

  floatx4 acc[8][4];
  const floatx4 zero = {0.f, 0.f, 0.f, 0.f};
#pragma unroll
  for (int i = 0; i < 8; ++i)
#pragma unroll
    for (int j = 0; j < 4; ++j) acc[i][j] = zero;

  bf16x8 bA[4], bB[4];

  gload_lds16(gA, lsA + dA); gA += BKn;
  LOADB4(bA, 16384);
  asm volatile("s_waitcnt vmcnt(0)\n\ts_barrier" ::: "memory");

#pragma unroll 1
  for (int it = 0; it < 7; ++it) {             // steps 0..13
    QSTEP(0, 1, bA, bB, true, 16384, "4");
    QSTEP(1, 0, bB, bA, true, 16384, "4");
  }
  QSTEP(0, 1, bA, bB, true,  16384, "4");      // step 14 (stages 15)
  QSTEP(1, 0, bB, bA, false, 16384, "0");      // step 15

#pragma unroll
  for (int mi = 0; mi < 8; ++mi)
#pragma unroll
    for (int r = 0; r < 4; ++r) {
      int row = mi * 16 + quad * 4 + r;
#pragma unroll
      for (int tc = 0; tc < 4; ++tc) {
        int col = wv * 64 + tc * 16 + l15;
        out[(size_t)(m0 + row) * Dn + col] = acc[mi][tc][r] + bo[col];
      }
    }
}

// ============================ workspace layout ==============================
static const size_t OFF_XPAD = 0;                     // 46,137,344 B (bf16 Xpad)
static const size_t OFF_WCT  = 46137344;              //  4,718,592 B (wctf)
static const size_t OFF_WOT  = 50855936;              //    524,288 B (wotf)
static const size_t OFF_WQFT = 51380224;              //     65,536 B
static const size_t OFF_QKV  = 51445760;              // 125,829,120 B
static const size_t OFF_QFP  = 177274880;             //  1,310,720 B
static const size_t OFF_BIAS = 178585600;             //     12,800 B
static const size_t OFF_AOUT = 0;                     // overlays Xpad (dead after k_qfqp/k_qkv)

extern "C" void kernel_launch(void* const* d_in, const int* in_sizes, int n_in,
                              void* d_out, int out_size, void* d_ws, size_t ws_size,
                              hipStream_t stream) {
  (void)in_sizes; (void)n_in; (void)out_size; (void)ws_size;
  const float* x     = (const float*)d_in[0];
  const float* Wq    = (const float*)d_in[1];
  const float* Wk    = (const float*)d_in[2];
  const float* Wv    = (const float*)d_in[3];
  const float* gq_g  = (const float*)d_in[4];
  const float* gq_b  = (const float*)d_in[5];
  const float* gk_g  = (const float*)d_in[6];
  const float* gk_b  = (const float*)d_in[7];
  const float* gv_g  = (const float*)d_in[8];
  const float* gv_b  = (const float*)d_in[9];
  const float* rel   = (const float*)d_in[10];
  const float* gsb   = (const float*)d_in[11];
  const float* alpha = (const float*)d_in[12];
  const float* Wqf   = (const float*)d_in[13];
  const float* bqf   = (const float*)d_in[14];
  const float* Wqp   = (const float*)d_in[15];
  const float* bqp   = (const float*)d_in[16];
  const float* Wo    = (const float*)d_in[17];
  const float* bo    = (const float*)d_in[18];
  float* out = (float*)d_out;
  char* ws = (char*)d_ws;

  __bf16* xpad = (__bf16*)(ws + OFF_XPAD);
  __bf16* wctf = (__bf16*)(ws + OFF_WCT);
  __bf16* wotf = (__bf16*)(ws + OFF_WOT);
  __bf16* wqft = (__bf16*)(ws + OFF_WQFT);
  __bf16* qkv  = (__bf16*)(ws + OFF_QKV);
  float*  qfp  = (float*)(ws + OFF_QFP);
  float*  bias = (float*)(ws + OFF_BIAS);
  __bf16* aout = (__bf16*)(ws + OFF_AOUT);

  k_prep_xpad<<<(Bn * NPn * (Dn / 8) + 255) / 256, 256, 0, stream>>>(x, xpad);
  k_prep_wctf<<<(48 * 96 * 64 + 255) / 256, 256, 0, stream>>>(Wq, Wk, Wv, wctf);
  k_prep_wotf<<<(16 * 32 * 64 + 255) / 256, 256, 0, stream>>>(Wo, wotf);
  k_prep_wqft<<<(Dn * 64 + 255) / 256, 256, 0, stream>>>(Wqf, wqft);
  k_bias     <<<(Hn * Nn * Nn + 255) / 256, 256, 0, stream>>>(rel, gsb, alpha, bqp, bias);

  k_qkv <<<Mn / 128 * 3, 512, 0, stream>>>(xpad, wctf, gq_g, gq_b, gk_g, gk_b, gv_g, gv_b, qkv);
  k_qfqp<<<Mn / 64, 256, 0, stream>>>(xpad, wqft, bqf, Wqp, qfp);
  k_attn<<<(Bn * Hn) / 4, 256, 0, stream>>>(qkv, qfp, bias, aout);
  k_oproj<<<Mn / 128, 512, 0, stream>>>(aout, wotf, bo, out);
}